// Round 10
// baseline (406.716 us; speedup 1.0000x reference)
//
#include <hip/hip_runtime.h>
#include <hip/hip_bf16.h>
#include <stdint.h>

#define S_LEN 2048
#define B_SZ  16
#define D_DIM 1024
#define H_DIM 1024
#define M_TOT (S_LEN * B_SZ)      // 32768
#define N_TOT (3 * H_DIM)         // 3072
#define K_TOT D_DIM               // 1024

// ---- GEMM geometry: 256x256 tile, BK=64, 8 waves (2Mx4N), 512 threads ----
#define BM 256
#define BN 256
#define BK 64
#define NT   (K_TOT / BK)         // 16 K-tiles
#define NTN  (N_TOT / BN)         // 12
#define NWG  ((M_TOT / BM) * NTN) // 1536 (divisible by 8 -> simple XCD swizzle)

#define NCHUNK 32
#define CLEN   64                 // NCHUNK*CLEN == S_LEN
#define NCH    (B_SZ * H_DIM)     // 16384 independent channels

typedef __attribute__((ext_vector_type(8))) short short8;
typedef __attribute__((ext_vector_type(4))) float f32x4;

// ---------- helpers ----------
__device__ __forceinline__ void gload_lds16(const void* g, void* l) {
  __builtin_amdgcn_global_load_lds((__attribute__((address_space(1))) void*)g,
                                   (__attribute__((address_space(3))) void*)l,
                                   16, 0, 0);
}

__device__ __forceinline__ unsigned short f2bfbits(float x) {
  union { __hip_bfloat16 h; unsigned short u; } cv;
  cv.h = __float2bfloat16(x);
  return cv.u;
}

__device__ __forceinline__ float bfbits2f(unsigned short u) {
  union { float f; unsigned int v; } cv;
  cv.v = ((unsigned int)u) << 16;
  return cv.f;
}

// cheap native sigmoid/tanh (v_exp + v_rcp)
__device__ __forceinline__ float sig_fast(float y) {
  float e = __expf(y);
  return e * __builtin_amdgcn_rcpf(1.f + e);
}
__device__ __forceinline__ float tanh_fast(float y) {
  float e = __expf(2.f * y);
  return 2.f * (e * __builtin_amdgcn_rcpf(1.f + e)) - 1.f;
}

// ---------- fp32 -> bf16 conversion (vectorized) ----------
__global__ void cvt_kernel(const float* __restrict__ in,
                           unsigned short* __restrict__ out, int n4) {
  int i = blockIdx.x * 256 + threadIdx.x;
  if (i < n4) {
    float4 v = ((const float4*)in)[i];
    ushort4 o;
    o.x = f2bfbits(v.x); o.y = f2bfbits(v.y);
    o.z = f2bfbits(v.z); o.w = f2bfbits(v.w);
    ((ushort4*)out)[i] = o;
  }
}

// ---------- GEMM: Y = Xb * Wb^T + bias -> raw bf16 Y chunks ----------
// (byte-identical to R9: 4 phases/K-tile, rotating half-stage + vmcnt(6))
__global__ __launch_bounds__(512, 2) void gemm_act(
    const __hip_bfloat16* __restrict__ Xb,
    const __hip_bfloat16* __restrict__ Wb,
    const float* __restrict__ bias,
    unsigned short* __restrict__ wsZ,
    unsigned short* __restrict__ wsF,
    unsigned short* __restrict__ wsO) {
  __shared__ __align__(16) char lds[131072];

  int bid = blockIdx.x;
  int swz = (bid & 7) * (NWG >> 3) + (bid >> 3);   // XCD-aware, bijective
  int tm  = swz / NTN;
  int tn  = swz - tm * NTN;
  const int m0 = tm * BM;
  const int n0 = tn * BN;

  const int tid  = threadIdx.x;
  const int lane = tid & 63;
  const int wid  = tid >> 6;
  const int wr   = wid >> 2;        // 0..1 : wave row  (128 rows each)
  const int wc   = wid & 3;         // 0..3 : wave col  (64 cols each)
  const int lr   = lane & 15;
  const int lg   = lane >> 4;

  const char* Ab = (const char*)(Xb + (size_t)m0 * K_TOT);
  const char* Bb = (const char*)(Wb + (size_t)n0 * K_TOT);

  f32x4 acc[8][4];
  const f32x4 vz = {0.f, 0.f, 0.f, 0.f};
  #pragma unroll
  for (int m = 0; m < 8; ++m)
    #pragma unroll
    for (int n = 0; n < 4; ++n) acc[m][n] = vz;

  #define STAGE_A(tt, h)                                                      \
    {                                                                         \
      char* l = lds + (((tt) & 1) << 15);                                     \
      _Pragma("unroll")                                                       \
      for (int j = 0; j < 2; ++j) {                                           \
        int r = j * 128 + (h) * 64 + (tid >> 3);                              \
        gload_lds16(Ab + (size_t)r * (K_TOT * 2) + (size_t)(tt) * (BK * 2)    \
                       + (((tid & 7) ^ (r & 7)) << 4),                        \
                    l + r * 128 + ((tid & 7) << 4));                          \
      }                                                                       \
    }

  #define STAGE_B(tt, h)                                                      \
    {                                                                         \
      char* l = lds + 65536 + (((tt) & 1) << 15);                             \
      int u = tid >> 3;                                                       \
      _Pragma("unroll")                                                       \
      for (int j = 0; j < 2; ++j) {                                           \
        int r = j * 128 + (h) * 32 + (u & 31) + (u >> 5) * 64;                \
        gload_lds16(Bb + (size_t)r * (K_TOT * 2) + (size_t)(tt) * (BK * 2)    \
                       + (((tid & 7) ^ (r & 7)) << 4),                        \
                    l + r * 128 + ((tid & 7) << 4));                          \
      }                                                                       \
    }

  #define BAR()                                                               \
    { asm volatile("" ::: "memory");                                          \
      __builtin_amdgcn_s_barrier();                                           \
      asm volatile("" ::: "memory"); }

  #define LGKM0()                                                             \
    { asm volatile("s_waitcnt lgkmcnt(0)" ::: "memory");                      \
      __builtin_amdgcn_sched_barrier(0); }

  #define VMC(n)                                                              \
    { asm volatile("s_waitcnt vmcnt(" #n ")" ::: "memory");                   \
      __builtin_amdgcn_sched_barrier(0); }

  #define READ_A(dst, tb, mh)                                                 \
    _Pragma("unroll")                                                         \
    for (int mm = 0; mm < 4; ++mm)                                            \
      _Pragma("unroll")                                                       \
      for (int ks = 0; ks < 2; ++ks) {                                        \
        int row = wr * 128 + (mh) * 64 + mm * 16 + lr;                        \
        dst[mm][ks] = *(const short8*)(lds + ((tb) << 15) + row * 128 +       \
                                       ((((ks << 2) | lg) ^ (row & 7)) << 4));\
      }

  #define READ_B(dst, tb, nh)                                                 \
    _Pragma("unroll")                                                         \
    for (int nn = 0; nn < 2; ++nn)                                            \
      _Pragma("unroll")                                                       \
      for (int ks = 0; ks < 2; ++ks) {                                        \
        int row = wc * 64 + (nh) * 32 + nn * 16 + lr;                         \
        dst[nn][ks] = *(const short8*)(lds + 65536 + ((tb) << 15) +           \
                                       row * 128 +                            \
                                       ((((ks << 2) | lg) ^ (row & 7)) << 4));\
      }

  #define MFMA_Q(mh, nh, A, Bf)                                               \
    __builtin_amdgcn_s_setprio(1);                                            \
    _Pragma("unroll")                                                         \
    for (int ks = 0; ks < 2; ++ks)                                            \
      _Pragma("unroll")                                                       \
      for (int mm = 0; mm < 4; ++mm)                                          \
        _Pragma("unroll")                                                     \
        for (int nn = 0; nn < 2; ++nn)                                        \
          acc[(mh) * 4 + mm][(nh) * 2 + nn] =                                 \
              __builtin_amdgcn_mfma_f32_16x16x32_bf16(                        \
                  A[mm][ks], Bf[nn][ks], acc[(mh) * 4 + mm][(nh) * 2 + nn],   \
                  0, 0, 0);                                                   \
    __builtin_amdgcn_s_setprio(0);

  STAGE_A(0, 0);
  STAGE_B(0, 0);
  STAGE_B(0, 1);
  STAGE_A(0, 1);
  STAGE_B(1, 0);
  VMC(6);
  BAR();

  short8 afr[4][2], bfr0[2][2], bfr1[2][2];
  READ_B(bfr0, 0, 0);

  for (int t = 0; t < NT; ++t) {
    const int tb = t & 1;
    READ_A(afr, tb, 0);
    if (t + 1 < NT) { STAGE_A(t + 1, 0); VMC(6); } else { VMC(2); }
    BAR();
    LGKM0();
    MFMA_Q(0, 0, afr, bfr0);
    READ_B(bfr1, tb, 1);
    if (t + 1 < NT) { STAGE_B(t + 1, 1); VMC(6); } else { VMC(0); }
    BAR();
    LGKM0();
    MFMA_Q(0, 1, afr, bfr1);
    READ_A(afr, tb, 1);
    if (t + 1 < NT) { STAGE_A(t + 1, 1); VMC(6); } else { VMC(0); }
    BAR();
    LGKM0();
    MFMA_Q(1, 1, afr, bfr1);
    if (t + 2 < NT)      { STAGE_B(t + 2, 0); VMC(6); }
    else if (t + 1 < NT) { VMC(4); }
    else                 { VMC(0); }
    BAR();
    LGKM0();
    MFMA_Q(1, 0, afr, bfr0);
    if (t + 1 < NT) READ_B(bfr0, tb ^ 1, 0);
  }

  // ---- epilogue: bias only -> raw bf16 Y -> LDS -> coalesced stores ----
  const int chunk = n0 >> 10;
  const int hbase = (n0 & (H_DIM - 1)) + wc * 64;
  unsigned short* dst = (chunk == 0) ? wsZ : (chunk == 1) ? wsF : wsO;

  BAR();
  char* ep = lds + wid * 16384;
  float bv[4];
  #pragma unroll
  for (int n = 0; n < 4; ++n) bv[n] = bias[n0 + wc * 64 + n * 16 + lr];

  #pragma unroll
  for (int m = 0; m < 8; ++m)
    #pragma unroll
    for (int n = 0; n < 4; ++n)
      #pragma unroll
      for (int r = 0; r < 4; ++r) {
        int rowl = m * 16 + lg * 4 + r;
        *(unsigned short*)(ep + rowl * 128 + ((n * 16 + lr) << 1)) =
            f2bfbits(acc[m][n][r] + bv[n]);
      }

  #pragma unroll
  for (int it = 0; it < 16; ++it) {
    int rl = it * 8 + (lane >> 3);
    short8 v = *(const short8*)(ep + rl * 128 + ((lane & 7) << 4));
    size_t grow = (size_t)(m0 + wr * 128 + rl);
    *(short8*)((char*)dst + (grow * H_DIM + hbase) * 2 + ((lane & 7) << 4)) = v;
  }
}

// ---------- blocked scan pass 1: 8 channels/thread, short8 loads ----------
__global__ void scan_pass1(const unsigned short* __restrict__ F,
                           const unsigned short* __restrict__ Z,
                           float* __restrict__ chP, float* __restrict__ chA) {
  int t   = blockIdx.x * 256 + threadIdx.x;   // 0 .. NCHUNK*NCH/8-1 (65536)
  int ch8 = (t & (NCH / 8 - 1)) * 8;
  int c   = t >> 11;
  size_t base = (size_t)c * CLEN * NCH + ch8;
  float P[8], A[8];
  #pragma unroll
  for (int j = 0; j < 8; ++j) { P[j] = 1.f; A[j] = 0.f; }
  #pragma unroll 4
  for (int i = 0; i < CLEN; ++i) {
    short8 fv = *(const short8*)(F + base + (size_t)i * NCH);
    short8 zv = *(const short8*)(Z + base + (size_t)i * NCH);
    #pragma unroll
    for (int j = 0; j < 8; ++j) {
      float f = sig_fast(bfbits2f((unsigned short)fv[j]));
      float z = tanh_fast(bfbits2f((unsigned short)zv[j]));
      A[j] = fmaf(f, A[j], (1.f - f) * z);
      P[j] *= f;
    }
  }
  #pragma unroll
  for (int j = 0; j < 8; j += 4) {
    float4 p = {P[j], P[j + 1], P[j + 2], P[j + 3]};
    float4 a = {A[j], A[j + 1], A[j + 2], A[j + 3]};
    *(float4*)(chP + (size_t)c * NCH + ch8 + j) = p;
    *(float4*)(chA + (size_t)c * NCH + ch8 + j) = a;
  }
}

// ---------- mid scan: 4 channels/thread, float4 ----------
__global__ void scan_mid(const float* __restrict__ chP, const float* __restrict__ chA,
                         const float* __restrict__ hidden,
                         float* __restrict__ Cst, float* __restrict__ outLast) {
  int ch4 = (blockIdx.x * 256 + threadIdx.x) * 4;  // 0..16380
  float4 c0 = *(const float4*)(hidden + ch4);
  #pragma unroll
  for (int c = 0; c < NCHUNK; ++c) {
    *(float4*)(Cst + (size_t)c * NCH + ch4) = c0;
    float4 p = *(const float4*)(chP + (size_t)c * NCH + ch4);
    float4 a = *(const float4*)(chA + (size_t)c * NCH + ch4);
    c0.x = fmaf(p.x, c0.x, a.x);
    c0.y = fmaf(p.y, c0.y, a.y);
    c0.z = fmaf(p.z, c0.z, a.z);
    c0.w = fmaf(p.w, c0.w, a.w);
  }
  *(float4*)(outLast + ch4) = c0;
}

// ---------- pass 2: 8 channels/thread; fuse Hout = sig(O)*C ----------
__global__ void scan_pass2(const unsigned short* __restrict__ F,
                           const unsigned short* __restrict__ Z,
                           const unsigned short* __restrict__ O,
                           const float* __restrict__ Cst,
                           float* __restrict__ out) {
  int t   = blockIdx.x * 256 + threadIdx.x;
  int ch8 = (t & (NCH / 8 - 1)) * 8;
  int c   = t >> 11;
  size_t base = (size_t)c * CLEN * NCH + ch8;
  float C[8];
  #pragma unroll
  for (int j = 0; j < 8; j += 4) {
    float4 v = *(const float4*)(Cst + (size_t)c * NCH + ch8 + j);
    C[j] = v.x; C[j + 1] = v.y; C[j + 2] = v.z; C[j + 3] = v.w;
  }
  #pragma unroll 4
  for (int i = 0; i < CLEN; ++i) {
    short8 fv = *(const short8*)(F + base + (size_t)i * NCH);
    short8 zv = *(const short8*)(Z + base + (size_t)i * NCH);
    short8 ov = *(const short8*)(O + base + (size_t)i * NCH);
    float ho[8];
    #pragma unroll
    for (int j = 0; j < 8; ++j) {
      float f = sig_fast(bfbits2f((unsigned short)fv[j]));
      float z = tanh_fast(bfbits2f((unsigned short)zv[j]));
      C[j] = fmaf(f, C[j], (1.f - f) * z);
      ho[j] = sig_fast(bfbits2f((unsigned short)ov[j])) * C[j];
    }
    #pragma unroll
    for (int j = 0; j < 8; j += 4) {
      float4 w = {ho[j], ho[j + 1], ho[j + 2], ho[j + 3]};
      *(float4*)(out + base + (size_t)i * NCH + j) = w;
    }
  }
}

extern "C" void kernel_launch(void* const* d_in, const int* in_sizes, int n_in,
                              void* d_out, int out_size, void* d_ws, size_t ws_size,
                              hipStream_t stream) {
  const float* X      = (const float*)d_in[0];  // [S,B,D]
  const float* hidden = (const float*)d_in[1];  // [B,H]
  const float* W      = (const float*)d_in[2];  // [3H,D]
  const float* bias   = (const float*)d_in[3];  // [3H]
  float* out = (float*)d_out;                   // Hout [S,B,H] then C_last [1,B,H]

  char* ws = (char*)d_ws;
  __hip_bfloat16* Xb  = (__hip_bfloat16*)(ws);                 // 67,108,864
  __hip_bfloat16* Wb  = (__hip_bfloat16*)(ws + 67108864);      //  6,291,456
  unsigned short* wsZ = (unsigned short*)(ws + 73400320);      // 67,108,864 (raw Y bf16)
  unsigned short* wsF = (unsigned short*)(ws + 140509184);     // 67,108,864
  unsigned short* wsO = (unsigned short*)(ws + 207618048);     // 67,108,864
  float* chP = (float*)(ws + 274726912);                       //  2,097,152
  float* chA = (float*)(ws + 276824064);                       //  2,097,152
  float* Cst = (float*)(ws + 278921216);                       //  2,097,152

  // 1) convert X and W to bf16
  cvt_kernel<<<(M_TOT * K_TOT / 4 + 255) / 256, 256, 0, stream>>>(X, (unsigned short*)Xb, M_TOT * K_TOT / 4);
  cvt_kernel<<<(N_TOT * K_TOT / 4 + 255) / 256, 256, 0, stream>>>(W, (unsigned short*)Wb, N_TOT * K_TOT / 4);

  // 2) fused GEMM + bias (raw Y out; activations deferred to scans)
  gemm_act<<<NWG, 512, 0, stream>>>(Xb, Wb, bias, wsZ, wsF, wsO);

  // 3) blocked linear scan (vectorized 8 ch/thread; activations fused here)
  scan_pass1<<<(NCHUNK * NCH / 8) / 256, 256, 0, stream>>>(wsF, wsZ, chP, chA);
  scan_mid<<<(NCH / 4) / 256, 256, 0, stream>>>(chP, chA, hidden, Cst,
                                                out + (size_t)M_TOT * H_DIM);
  scan_pass2<<<(NCHUNK * NCH / 8) / 256, 256, 0, stream>>>(wsF, wsZ, wsO, Cst, out);
}

// Round 11
// 350.013 us; speedup vs baseline: 1.1620x; 1.1620x over previous
//
#include <hip/hip_runtime.h>
#include <hip/hip_bf16.h>
#include <stdint.h>

#define S_LEN 2048
#define B_SZ  16
#define D_DIM 1024
#define H_DIM 1024
#define M_TOT (S_LEN * B_SZ)      // 32768
#define N_TOT (3 * H_DIM)         // 3072
#define K_TOT D_DIM               // 1024

// ---- GEMM geometry: 256x256 tile, BK=64, 8 waves (2Mx4N), 512 threads ----
#define BM 256
#define BN 256
#define BK 64
#define NT   (K_TOT / BK)         // 16 K-tiles
#define NTN  (N_TOT / BN)         // 12
#define NWG  ((M_TOT / BM) * NTN) // 1536 (divisible by 8 -> simple XCD swizzle)

#define NCHUNK 64
#define CLEN   32                 // NCHUNK*CLEN == S_LEN
#define NCH    (B_SZ * H_DIM)     // 16384 independent channels

typedef __attribute__((ext_vector_type(8))) short short8;
typedef __attribute__((ext_vector_type(4))) float f32x4;

// ---------- helpers ----------
__device__ __forceinline__ void gload_lds16(const void* g, void* l) {
  __builtin_amdgcn_global_load_lds((__attribute__((address_space(1))) void*)g,
                                   (__attribute__((address_space(3))) void*)l,
                                   16, 0, 0);
}

__device__ __forceinline__ unsigned short f2bfbits(float x) {
  union { __hip_bfloat16 h; unsigned short u; } cv;
  cv.h = __float2bfloat16(x);
  return cv.u;
}

__device__ __forceinline__ float bfbits2f(unsigned short u) {
  union { float f; unsigned int v; } cv;
  cv.v = ((unsigned int)u) << 16;
  return cv.f;
}

// cheap native sigmoid/tanh (v_exp + v_rcp)
__device__ __forceinline__ float sig_fast(float y) {
  float e = __expf(y);
  return e * __builtin_amdgcn_rcpf(1.f + e);
}
__device__ __forceinline__ float tanh_fast(float y) {
  float e = __expf(2.f * y);
  return 2.f * (e * __builtin_amdgcn_rcpf(1.f + e)) - 1.f;
}

// ---------- fp32 -> bf16 conversion (vectorized) ----------
__global__ void cvt_kernel(const float* __restrict__ in,
                           unsigned short* __restrict__ out, int n4) {
  int i = blockIdx.x * 256 + threadIdx.x;
  if (i < n4) {
    float4 v = ((const float4*)in)[i];
    ushort4 o;
    o.x = f2bfbits(v.x); o.y = f2bfbits(v.y);
    o.z = f2bfbits(v.z); o.w = f2bfbits(v.w);
    ((ushort4*)out)[i] = o;
  }
}

// ---------- GEMM: Y = Xb * Wb^T + bias -> raw bf16 Y chunks ----------
// (byte-identical to R9: 4 phases/K-tile, rotating half-stage + vmcnt(6))
__global__ __launch_bounds__(512, 2) void gemm_act(
    const __hip_bfloat16* __restrict__ Xb,
    const __hip_bfloat16* __restrict__ Wb,
    const float* __restrict__ bias,
    unsigned short* __restrict__ wsZ,
    unsigned short* __restrict__ wsF,
    unsigned short* __restrict__ wsO) {
  __shared__ __align__(16) char lds[131072];

  int bid = blockIdx.x;
  int swz = (bid & 7) * (NWG >> 3) + (bid >> 3);   // XCD-aware, bijective
  int tm  = swz / NTN;
  int tn  = swz - tm * NTN;
  const int m0 = tm * BM;
  const int n0 = tn * BN;

  const int tid  = threadIdx.x;
  const int lane = tid & 63;
  const int wid  = tid >> 6;
  const int wr   = wid >> 2;        // 0..1 : wave row  (128 rows each)
  const int wc   = wid & 3;         // 0..3 : wave col  (64 cols each)
  const int lr   = lane & 15;
  const int lg   = lane >> 4;

  const char* Ab = (const char*)(Xb + (size_t)m0 * K_TOT);
  const char* Bb = (const char*)(Wb + (size_t)n0 * K_TOT);

  f32x4 acc[8][4];
  const f32x4 vz = {0.f, 0.f, 0.f, 0.f};
  #pragma unroll
  for (int m = 0; m < 8; ++m)
    #pragma unroll
    for (int n = 0; n < 4; ++n) acc[m][n] = vz;

  #define STAGE_A(tt, h)                                                      \
    {                                                                         \
      char* l = lds + (((tt) & 1) << 15);                                     \
      _Pragma("unroll")                                                       \
      for (int j = 0; j < 2; ++j) {                                           \
        int r = j * 128 + (h) * 64 + (tid >> 3);                              \
        gload_lds16(Ab + (size_t)r * (K_TOT * 2) + (size_t)(tt) * (BK * 2)    \
                       + (((tid & 7) ^ (r & 7)) << 4),                        \
                    l + r * 128 + ((tid & 7) << 4));                          \
      }                                                                       \
    }

  #define STAGE_B(tt, h)                                                      \
    {                                                                         \
      char* l = lds + 65536 + (((tt) & 1) << 15);                             \
      int u = tid >> 3;                                                       \
      _Pragma("unroll")                                                       \
      for (int j = 0; j < 2; ++j) {                                           \
        int r = j * 128 + (h) * 32 + (u & 31) + (u >> 5) * 64;                \
        gload_lds16(Bb + (size_t)r * (K_TOT * 2) + (size_t)(tt) * (BK * 2)    \
                       + (((tid & 7) ^ (r & 7)) << 4),                        \
                    l + r * 128 + ((tid & 7) << 4));                          \
      }                                                                       \
    }

  #define BAR()                                                               \
    { asm volatile("" ::: "memory");                                          \
      __builtin_amdgcn_s_barrier();                                           \
      asm volatile("" ::: "memory"); }

  #define LGKM0()                                                             \
    { asm volatile("s_waitcnt lgkmcnt(0)" ::: "memory");                      \
      __builtin_amdgcn_sched_barrier(0); }

  #define VMC(n)                                                              \
    { asm volatile("s_waitcnt vmcnt(" #n ")" ::: "memory");                   \
      __builtin_amdgcn_sched_barrier(0); }

  #define READ_A(dst, tb, mh)                                                 \
    _Pragma("unroll")                                                         \
    for (int mm = 0; mm < 4; ++mm)                                            \
      _Pragma("unroll")                                                       \
      for (int ks = 0; ks < 2; ++ks) {                                        \
        int row = wr * 128 + (mh) * 64 + mm * 16 + lr;                        \
        dst[mm][ks] = *(const short8*)(lds + ((tb) << 15) + row * 128 +       \
                                       ((((ks << 2) | lg) ^ (row & 7)) << 4));\
      }

  #define READ_B(dst, tb, nh)                                                 \
    _Pragma("unroll")                                                         \
    for (int nn = 0; nn < 2; ++nn)                                            \
      _Pragma("unroll")                                                       \
      for (int ks = 0; ks < 2; ++ks) {                                        \
        int row = wc * 64 + (nh) * 32 + nn * 16 + lr;                         \
        dst[nn][ks] = *(const short8*)(lds + 65536 + ((tb) << 15) +           \
                                       row * 128 +                            \
                                       ((((ks << 2) | lg) ^ (row & 7)) << 4));\
      }

  #define MFMA_Q(mh, nh, A, Bf)                                               \
    __builtin_amdgcn_s_setprio(1);                                            \
    _Pragma("unroll")                                                         \
    for (int ks = 0; ks < 2; ++ks)                                            \
      _Pragma("unroll")                                                       \
      for (int mm = 0; mm < 4; ++mm)                                          \
        _Pragma("unroll")                                                     \
        for (int nn = 0; nn < 2; ++nn)                                        \
          acc[(mh) * 4 + mm][(nh) * 2 + nn] =                                 \
              __builtin_amdgcn_mfma_f32_16x16x32_bf16(                        \
                  A[mm][ks], Bf[nn][ks], acc[(mh) * 4 + mm][(nh) * 2 + nn],   \
                  0, 0, 0);                                                   \
    __builtin_amdgcn_s_setprio(0);

  STAGE_A(0, 0);
  STAGE_B(0, 0);
  STAGE_B(0, 1);
  STAGE_A(0, 1);
  STAGE_B(1, 0);
  VMC(6);
  BAR();

  short8 afr[4][2], bfr0[2][2], bfr1[2][2];
  READ_B(bfr0, 0, 0);

  for (int t = 0; t < NT; ++t) {
    const int tb = t & 1;
    READ_A(afr, tb, 0);
    if (t + 1 < NT) { STAGE_A(t + 1, 0); VMC(6); } else { VMC(2); }
    BAR();
    LGKM0();
    MFMA_Q(0, 0, afr, bfr0);
    READ_B(bfr1, tb, 1);
    if (t + 1 < NT) { STAGE_B(t + 1, 1); VMC(6); } else { VMC(0); }
    BAR();
    LGKM0();
    MFMA_Q(0, 1, afr, bfr1);
    READ_A(afr, tb, 1);
    if (t + 1 < NT) { STAGE_A(t + 1, 1); VMC(6); } else { VMC(0); }
    BAR();
    LGKM0();
    MFMA_Q(1, 1, afr, bfr1);
    if (t + 2 < NT)      { STAGE_B(t + 2, 0); VMC(6); }
    else if (t + 1 < NT) { VMC(4); }
    else                 { VMC(0); }
    BAR();
    LGKM0();
    MFMA_Q(1, 0, afr, bfr0);
    if (t + 1 < NT) READ_B(bfr0, tb ^ 1, 0);
  }

  // ---- epilogue: bias only -> raw bf16 Y -> LDS -> coalesced stores ----
  const int chunk = n0 >> 10;
  const int hbase = (n0 & (H_DIM - 1)) + wc * 64;
  unsigned short* dst = (chunk == 0) ? wsZ : (chunk == 1) ? wsF : wsO;

  BAR();
  char* ep = lds + wid * 16384;
  float bv[4];
  #pragma unroll
  for (int n = 0; n < 4; ++n) bv[n] = bias[n0 + wc * 64 + n * 16 + lr];

  #pragma unroll
  for (int m = 0; m < 8; ++m)
    #pragma unroll
    for (int n = 0; n < 4; ++n)
      #pragma unroll
      for (int r = 0; r < 4; ++r) {
        int rowl = m * 16 + lg * 4 + r;
        *(unsigned short*)(ep + rowl * 128 + ((n * 16 + lr) << 1)) =
            f2bfbits(acc[m][n][r] + bv[n]);
      }

  #pragma unroll
  for (int it = 0; it < 16; ++it) {
    int rl = it * 8 + (lane >> 3);
    short8 v = *(const short8*)(ep + rl * 128 + ((lane & 7) << 4));
    size_t grow = (size_t)(m0 + wr * 128 + rl);
    *(short8*)((char*)dst + (grow * H_DIM + hbase) * 2 + ((lane & 7) << 4)) = v;
  }
}

// ---------- scan pass 1: 4 ch/thread (8B/lane), 1024 blocks ----------
__global__ void scan_pass1(const unsigned short* __restrict__ F,
                           const unsigned short* __restrict__ Z,
                           float* __restrict__ chP, float* __restrict__ chA) {
  int t   = blockIdx.x * 256 + threadIdx.x;   // 0 .. NCHUNK*NCH/4-1 (262144)
  int ch4 = (t & (NCH / 4 - 1)) * 4;
  int c   = t >> 12;
  size_t base = (size_t)c * CLEN * NCH + ch4;
  float P[4] = {1.f, 1.f, 1.f, 1.f};
  float A[4] = {0.f, 0.f, 0.f, 0.f};
  #pragma unroll 4
  for (int i = 0; i < CLEN; ++i) {
    ushort4 fv = *(const ushort4*)(F + base + (size_t)i * NCH);
    ushort4 zv = *(const ushort4*)(Z + base + (size_t)i * NCH);
    unsigned short fa[4] = {fv.x, fv.y, fv.z, fv.w};
    unsigned short za[4] = {zv.x, zv.y, zv.z, zv.w};
    #pragma unroll
    for (int j = 0; j < 4; ++j) {
      float f = sig_fast(bfbits2f(fa[j]));
      float z = tanh_fast(bfbits2f(za[j]));
      A[j] = fmaf(f, A[j], (1.f - f) * z);
      P[j] *= f;
    }
  }
  float4 p = {P[0], P[1], P[2], P[3]};
  float4 a = {A[0], A[1], A[2], A[3]};
  *(float4*)(chP + (size_t)c * NCH + ch4) = p;
  *(float4*)(chA + (size_t)c * NCH + ch4) = a;
}

// ---------- mid scan: sequential over 64 chunks per channel ----------
__global__ void scan_mid(const float* __restrict__ chP, const float* __restrict__ chA,
                         const float* __restrict__ hidden,
                         float* __restrict__ Cst, float* __restrict__ outLast) {
  int ch = blockIdx.x * 256 + threadIdx.x;  // 0..16383
  float c0 = hidden[ch];
  #pragma unroll
  for (int c = 0; c < NCHUNK; ++c) {
    Cst[c * NCH + ch] = c0;
    c0 = fmaf(chP[c * NCH + ch], c0, chA[c * NCH + ch]);
  }
  outLast[ch] = c0;  // C[S-1] output (fp32)
}

// ---------- pass 2: 4 ch/thread; fuse Hout = sig(O)*C ----------
__global__ void scan_pass2(const unsigned short* __restrict__ F,
                           const unsigned short* __restrict__ Z,
                           const unsigned short* __restrict__ O,
                           const float* __restrict__ Cst,
                           float* __restrict__ out) {
  int t   = blockIdx.x * 256 + threadIdx.x;
  int ch4 = (t & (NCH / 4 - 1)) * 4;
  int c   = t >> 12;
  size_t base = (size_t)c * CLEN * NCH + ch4;
  float4 cv = *(const float4*)(Cst + (size_t)c * NCH + ch4);
  float C[4] = {cv.x, cv.y, cv.z, cv.w};
  #pragma unroll 4
  for (int i = 0; i < CLEN; ++i) {
    ushort4 fv = *(const ushort4*)(F + base + (size_t)i * NCH);
    ushort4 zv = *(const ushort4*)(Z + base + (size_t)i * NCH);
    ushort4 ov = *(const ushort4*)(O + base + (size_t)i * NCH);
    unsigned short fa[4] = {fv.x, fv.y, fv.z, fv.w};
    unsigned short za[4] = {zv.x, zv.y, zv.z, zv.w};
    unsigned short oa[4] = {ov.x, ov.y, ov.z, ov.w};
    float ho[4];
    #pragma unroll
    for (int j = 0; j < 4; ++j) {
      float f = sig_fast(bfbits2f(fa[j]));
      float z = tanh_fast(bfbits2f(za[j]));
      C[j] = fmaf(f, C[j], (1.f - f) * z);
      ho[j] = sig_fast(bfbits2f(oa[j])) * C[j];
    }
    float4 w = {ho[0], ho[1], ho[2], ho[3]};
    *(float4*)(out + base + (size_t)i * NCH) = w;
  }
}

extern "C" void kernel_launch(void* const* d_in, const int* in_sizes, int n_in,
                              void* d_out, int out_size, void* d_ws, size_t ws_size,
                              hipStream_t stream) {
  const float* X      = (const float*)d_in[0];  // [S,B,D]
  const float* hidden = (const float*)d_in[1];  // [B,H]
  const float* W      = (const float*)d_in[2];  // [3H,D]
  const float* bias   = (const float*)d_in[3];  // [3H]
  float* out = (float*)d_out;                   // Hout [S,B,H] then C_last [1,B,H]

  char* ws = (char*)d_ws;
  __hip_bfloat16* Xb  = (__hip_bfloat16*)(ws);                 // 67,108,864
  __hip_bfloat16* Wb  = (__hip_bfloat16*)(ws + 67108864);      //  6,291,456
  unsigned short* wsZ = (unsigned short*)(ws + 73400320);      // 67,108,864 (raw Y bf16)
  unsigned short* wsF = (unsigned short*)(ws + 140509184);     // 67,108,864
  unsigned short* wsO = (unsigned short*)(ws + 207618048);     // 67,108,864
  // scan scratch (NCHUNK=64 -> 4MB each) aliases the Xb region: Xb is dead
  // after gemm_act, and every call rewrites Xb (cvt) before gemm reads it.
  float* chP = (float*)(ws + 274726912);                       //  2,097,152 (c 0..31)
  float* chP2= (float*)(ws);                                   //  use Xb[0:2MB] for c 32..63
  (void)chP2;
  float* chA = (float*)(ws + 276824064);                       //  2,097,152
  float* Cst = (float*)(ws + 278921216);                       //  2,097,152
  // Simpler: place all three full-size arrays in the Xb alias region.
  chP = (float*)(ws);                                          // 4 MB
  chA = (float*)(ws + 4194304);                                // 4 MB
  Cst = (float*)(ws + 8388608);                                // 4 MB

  // 1) convert X and W to bf16
  cvt_kernel<<<(M_TOT * K_TOT / 4 + 255) / 256, 256, 0, stream>>>(X, (unsigned short*)Xb, M_TOT * K_TOT / 4);
  cvt_kernel<<<(N_TOT * K_TOT / 4 + 255) / 256, 256, 0, stream>>>(W, (unsigned short*)Wb, N_TOT * K_TOT / 4);

  // 2) fused GEMM + bias (raw Y out; activations deferred to scans)
  gemm_act<<<NWG, 512, 0, stream>>>(Xb, Wb, bias, wsZ, wsF, wsO);

  // 3) blocked linear scan (4 ch/thread, 16 waves/CU; activations fused here)
  scan_pass1<<<(NCHUNK * NCH / 4) / 256, 256, 0, stream>>>(wsF, wsZ, chP, chA);
  scan_mid<<<NCH / 256, 256, 0, stream>>>(chP, chA, hidden, Cst,
                                          out + (size_t)M_TOT * H_DIM);
  scan_pass2<<<(NCHUNK * NCH / 4) / 256, 256, 0, stream>>>(wsF, wsZ, wsO, Cst, out);
}